// Round 1
// baseline (362.012 us; speedup 1.0000x reference)
//
#include <hip/hip_runtime.h>

// MessagePassingConvolution, round 11.
// Pipeline unchanged (memset cnt -> build f16 records into CAP=96 buckets),
// NEW node kernel v11: zero-LDS streaming inner loop.
//  - records read at wave-uniform (scalar) addresses, prefetched 2 ahead
//  - sender nf elements loaded per-lane directly from global (L1/L2-resident
//    6.4 MB table; one wave-load touches one 128B row), prefetched 1 ahead
//  - 112-product / 2-slot lane mapping: no dead type2 reads, no duplicated
//    acc1 comps. Once-per-node LDS scratch epilogue merges type2 triples.
//
// Record (32 B): uint4 A = h[0..7] as 4x half2 ; uint4 B = {e0|e1x, e1y|e1z,
// snd, 0}. h = swish(r@w1)/sqrt(32); 1/sqrt(3) folded into per-lane w2 col.
//
// product table (112 products -> out[96]):
//  slot0 (64 lanes):
//   lanes  0..7 : out[c]=lane      k=lane    i=lane    f=1        (s*w)
//   lanes  8..15: out[c]=lane      k=lane    i=lane-8  f=e0       (s*e0*w)
//   lanes 16..39: t=lane-16, m=t/3, x=t%3 -> partial of out[16+m]:
//                 k=16+m (w*1/sqrt3) i=8+t   f=e1[x]   (dot(v,e1) terms)
//   lanes 40..63: t=lane-40 -> out[24+t]    k=24+t/3 i=8+t f=1    (v*w)
//  slot1 (48 lanes used):
//   lanes  0..23: t=lane, m=t/3, x=t%3 -> out[48+t] k=32+m i=m f=e1[x]
//   lanes 24..47: t=lane-24 -> out[72+t]   k=40+t/3 i=8+t   f=e0
//   lanes 48..63: dead (w cols zeroed)

#define CAPACITY 96

typedef _Float16 half2v __attribute__((ext_vector_type(2)));

__device__ __forceinline__ unsigned pk16(float a, float b) {
    return __builtin_bit_cast(unsigned, __builtin_amdgcn_cvt_pkrtz(a, b));
}

__device__ __forceinline__ float dot2h(unsigned a, half2v b, float c) {
#if __has_builtin(__builtin_amdgcn_fdot2)
    return __builtin_amdgcn_fdot2(__builtin_bit_cast(half2v, a), b, c, false);
#else
    half2v av = __builtin_bit_cast(half2v, a);
    return fmaf((float)av.x, (float)b.x, fmaf((float)av.y, (float)b.y, c));
#endif
}

__global__ __launch_bounds__(256) void hist_kernel(
    const int* __restrict__ recv, int* __restrict__ cnt, int E)
{
    int e = blockIdx.x * 256 + threadIdx.x;
    if (e < E) atomicAdd(&cnt[recv[e]], 1);
}

__global__ __launch_bounds__(1024) void scan_kernel(
    const int* __restrict__ cnt, int* __restrict__ off,
    int* __restrict__ cursor, int N)
{
    __shared__ int lds[1024];
    const int t = threadIdx.x;
    const int CHN = (N + 1023) / 1024;
    const int lo = t * CHN;
    const int hi = min(N, lo + CHN);
    int s = 0;
    for (int i = lo; i < hi; ++i) s += cnt[i];
    lds[t] = s;
    __syncthreads();
    for (int d = 1; d < 1024; d <<= 1) {
        int v = (t >= d) ? lds[t - d] : 0;
        __syncthreads();
        lds[t] += v;
        __syncthreads();
    }
    int run = (t > 0) ? lds[t - 1] : 0;
    for (int i = lo; i < hi; ++i) {
        off[i] = run;
        cursor[i] = run;
        run += cnt[i];
    }
    if (t == 1023) off[N] = lds[1023];
}

// Edge-parallel: radial MLP, pack 32-B f16 record, place at bucket/sorted slot.
__global__ __launch_bounds__(256) void build_recs_kernel(
    const float* __restrict__ edge_features, // E x 4
    const float* __restrict__ radial,        // E x 8
    const float* __restrict__ w1g,           // 8 x 8
    const int* __restrict__ senders,
    const int* __restrict__ recv,
    int* __restrict__ slots,                 // cnt (bucket) or cursor (sorted)
    uint4* __restrict__ recs,                // 2 x uint4 per record
    int E, int CAP)
{
    __shared__ float sw1[64];
    for (int i = threadIdx.x; i < 64; i += 256) sw1[i] = w1g[i];
    __syncthreads();

    int e = blockIdx.x * 256 + threadIdx.x;
    if (e >= E) return;

    const int rcv_ = recv[e];
    // atomic first: overlap its latency with the MLP
    size_t addr;
    if (CAP > 0) {
        int slot = atomicAdd(&slots[rcv_], 1);
        slot = min(slot, CAP - 1); // safety clamp (P(deg>96) ~ 1e-18/node)
        addr = (size_t)rcv_ * CAP + slot;
    } else {
        addr = (size_t)atomicAdd(&slots[rcv_], 1);
    }

    const float4 ef = reinterpret_cast<const float4*>(edge_features)[e];
    const float4 ra = reinterpret_cast<const float4*>(radial)[2 * e + 0];
    const float4 rb = reinterpret_cast<const float4*>(radial)[2 * e + 1];
    const int snd = senders[e];

    float r[8] = {ra.x, ra.y, ra.z, ra.w, rb.x, rb.y, rb.z, rb.w};
    float h[8];
#pragma unroll
    for (int j = 0; j < 8; ++j) {
        float x = 0.f;
#pragma unroll
        for (int i = 0; i < 8; ++i) x = fmaf(r[i], sw1[i * 8 + j], x);
        // swish with 1/sqrt(32) folded
        h[j] = 0.17677669529663687f * x * __builtin_amdgcn_rcpf(1.0f + __expf(-x));
    }

    uint4 qa, qb;
    qa.x = pk16(h[0], h[1]); qa.y = pk16(h[2], h[3]);
    qa.z = pk16(h[4], h[5]); qa.w = pk16(h[6], h[7]);
    qb.x = pk16(ef.x, ef.y); qb.y = pk16(ef.z, ef.w);
    qb.z = (unsigned)snd;    qb.w = 0u;
    recs[2 * addr + 0] = qa;
    recs[2 * addr + 1] = qb;
}

// One wave per node, 4 nodes/block, no barriers, no LDS in the inner loop.
template<bool CAPMODE>
__global__ __launch_bounds__(256) void node_v11_kernel(
    const float* __restrict__ node_feats,    // N x 32
    const float* __restrict__ w2g,           // 8 x 48
    const int* __restrict__ off,             // cnt[N] (CAPMODE) or off[N+1]
    const uint4* __restrict__ recs,
    float* __restrict__ out,                 // N x 96
    int N)
{
    const int lane = threadIdx.x & 63;
    const int wv   = threadIdx.x >> 6;   // 0..3 = local node
    const int node = blockIdx.x * 4 + wv;

    __shared__ float scr[4][128];            // 2 KB, wave-private epilogue scratch

    // ---- per-lane product-slot tables (all loop-invariant) ----
    int kA, iA, selA; float scA = 1.0f;
    if (lane < 8)       { kA = lane;         iA = lane;     selA = 0; }
    else if (lane < 16) { kA = lane;         iA = lane - 8; selA = 1; }
    else if (lane < 40) { int t = lane - 16; kA = 16 + t / 3; iA = 8 + t;
                          selA = 2 + t % 3;  scA = 0.57735026918962576f; }
    else                { int t = lane - 40; kA = 24 + t / 3; iA = 8 + t; selA = 0; }

    int kB, iB, selB; const bool deadB = (lane >= 48);
    if (lane < 24)      { int t = lane;      kB = 32 + t / 3; iB = t / 3; selB = 2 + t % 3; }
    else if (lane < 48) { int t = lane - 24; kB = 40 + t / 3; iB = 8 + t; selB = 1; }
    else                { kB = 0; iB = 0; selB = 0; }

    half2v wpA[4], wpB[4];
#pragma unroll
    for (int i = 0; i < 4; ++i) {
        wpA[i].x = (_Float16)(w2g[(2 * i + 0) * 48 + kA] * scA);
        wpA[i].y = (_Float16)(w2g[(2 * i + 1) * 48 + kA] * scA);
        wpB[i].x = deadB ? (_Float16)0.f : (_Float16)(w2g[(2 * i + 0) * 48 + kB]);
        wpB[i].y = deadB ? (_Float16)0.f : (_Float16)(w2g[(2 * i + 1) * 48 + kB]);
    }

    if (node >= N) return;  // safe: no __syncthreads in this kernel

    int base, count;
    if (CAPMODE) { base = node * CAPACITY; count = min(off[node], CAPACITY); }
    else         { base = off[node];       count = off[node + 1] - base; }
    base  = __builtin_amdgcn_readfirstlane(base);   // scalar-root the rec stream
    count = __builtin_amdgcn_readfirstlane(count);
    const uint4* rp = recs + (size_t)base * 2;

    float acc0 = 0.f, acc1 = 0.f;
    if (count > 0) {
        const int last = count - 1;
        // prologue: rec[0] now, rec[1], rec[2] in flight, nf[0] issued
        uint4 qaC = rp[0], qbC = rp[1];
        const int j1 = min(1, last), j2 = min(2, last);
        uint4 qaN1 = rp[2 * j1], qbN1 = rp[2 * j1 + 1];
        uint4 qaN2 = rp[2 * j2], qbN2 = rp[2 * j2 + 1];
        int snd0 = __builtin_amdgcn_readfirstlane((int)qbC.z);
        const float* row0 = node_feats + (size_t)snd0 * 32;
        float n0 = row0[iA];
        float n1 = row0[iB];

#pragma unroll 2
        for (int i = 0; i < count; ++i) {
            // issue nf prefetch for edge i+1 (uses rec[i+1], in flight 2 iters)
            const int sndN = __builtin_amdgcn_readfirstlane((int)qbN1.z);
            const float* rowN = node_feats + (size_t)sndN * 32;
            const float n0N = rowN[iA];
            const float n1N = rowN[iB];

            // ---- compute edge i (registers only) ----
            float wAv = dot2h(qaC.x, wpA[0], 0.f);
            wAv = dot2h(qaC.y, wpA[1], wAv);
            wAv = dot2h(qaC.z, wpA[2], wAv);
            wAv = dot2h(qaC.w, wpA[3], wAv);
            float wBv = dot2h(qaC.x, wpB[0], 0.f);
            wBv = dot2h(qaC.y, wpB[1], wBv);
            wBv = dot2h(qaC.z, wpB[2], wBv);
            wBv = dot2h(qaC.w, wpB[3], wBv);

            const half2v eA = __builtin_bit_cast(half2v, qbC.x);
            const half2v eB = __builtin_bit_cast(half2v, qbC.y);
            const float e0  = (float)eA.x, e1x = (float)eA.y;
            const float e1y = (float)eB.x, e1z = (float)eB.y;

            const float fA = (selA == 0) ? 1.0f
                           : (selA == 1) ? e0
                           : (selA == 2) ? e1x
                           : (selA == 3) ? e1y : e1z;
            const float fB = (selB == 1) ? e0
                           : (selB == 2) ? e1x
                           : (selB == 3) ? e1y : e1z;

            acc0 = fmaf(wAv, n0 * fA, acc0);
            acc1 = fmaf(wBv, n1 * fB, acc1);

            // rotate pipeline; issue rec prefetch for i+3
            qaC = qaN1; qbC = qbN1;
            qaN1 = qaN2; qbN1 = qbN2;
            n0 = n0N; n1 = n1N;
            const int jp = min(i + 3, last);
            qaN2 = rp[2 * jp]; qbN2 = rp[2 * jp + 1];
        }
    }

    // ---- epilogue: merge type2 triples, permute to output layout ----
    scr[wv][lane]      = acc0;
    scr[wv][64 + lane] = acc1;
    // same-wave LDS: no barrier needed, compiler inserts lgkmcnt waits
    float o0;
    if (lane < 16) {
        o0 = scr[wv][lane];
    } else if (lane < 24) {
        const int t = 16 + 3 * (lane - 16);
        o0 = scr[wv][t] + scr[wv][t + 1] + scr[wv][t + 2];
    } else {
        o0 = scr[wv][lane + 16];   // comps 24..47 <- slot0[40+..]; 48..63 <- slot1[0..15]
    }
    float* orow = out + (size_t)node * 96;
    orow[lane] = o0;
    if (lane < 32) orow[64 + lane] = scr[wv][80 + lane];  // comps 64..95 <- slot1[16..47]
}

extern "C" void kernel_launch(void* const* d_in, const int* in_sizes, int n_in,
                              void* d_out, int out_size, void* d_ws, size_t ws_size,
                              hipStream_t stream) {
    const float* node_feats    = (const float*)d_in[0];
    const float* edge_features = (const float*)d_in[1];
    const float* radial        = (const float*)d_in[2];
    const float* w1            = (const float*)d_in[3];
    const float* w2            = (const float*)d_in[4];
    const int*   senders       = (const int*)d_in[5];
    const int*   receivers     = (const int*)d_in[6];
    float* out = (float*)d_out;

    const int E = in_sizes[5];
    const int N = out_size / 96;
    const int eblocks = (E + 255) / 256;
    const int nblocks = (N + 3) / 4;   // 4 nodes/block, 1 wave/node

    const size_t needP1 = (size_t)N * CAPACITY * 32 + (size_t)N * sizeof(int);

    if (ws_size >= needP1) {
        // P1 (best known): capacity buckets. layout: recs[N*CAP*32 B] | cnt[N]
        uint4* recs = (uint4*)d_ws;
        int* cnt = (int*)((char*)d_ws + (size_t)N * CAPACITY * 32);

        (void)hipMemsetAsync(cnt, 0, (size_t)N * sizeof(int), stream);
        hipLaunchKernelGGL(build_recs_kernel, dim3(eblocks), dim3(256), 0, stream,
                           edge_features, radial, w1, senders, receivers,
                           cnt, recs, E, CAPACITY);
        hipLaunchKernelGGL(node_v11_kernel<true>, dim3(nblocks), dim3(256), 0, stream,
                           node_feats, w2, cnt, recs, out, N);
    } else {
        // P2 fallback: counting sort. layout: recs[E*32] | cnt[N] | off[N+1] | cursor[N]
        uint4* recs = (uint4*)d_ws;
        int* cnt    = (int*)((char*)d_ws + (size_t)E * 32);
        int* off    = cnt + N;
        int* cursor = cnt + 2 * N + 1;

        (void)hipMemsetAsync(cnt, 0, (size_t)N * sizeof(int), stream);
        hipLaunchKernelGGL(hist_kernel, dim3(eblocks), dim3(256), 0, stream,
                           receivers, cnt, E);
        hipLaunchKernelGGL(scan_kernel, dim3(1), dim3(1024), 0, stream,
                           cnt, off, cursor, N);
        hipLaunchKernelGGL(build_recs_kernel, dim3(eblocks), dim3(256), 0, stream,
                           edge_features, radial, w1, senders, receivers,
                           cursor, recs, E, 0);
        hipLaunchKernelGGL(node_v11_kernel<false>, dim3(nblocks), dim3(256), 0, stream,
                           node_feats, w2, off, recs, out, N);
    }
}

// Round 2
// 325.098 us; speedup vs baseline: 1.1135x; 1.1135x over previous
//
#include <hip/hip_runtime.h>

// MessagePassingConvolution, round 12.
// Pipeline unchanged (memset cnt -> build f16 records into CAP=96 buckets).
// Node kernel v12 = hybrid: v10's chunked bulk LDS staging (proven latency
// hiding, 90% VALUBusy) + v11's 112-product lane mapping (no duplicated
// acc1 work, no dead type2 reads, 1 product per lane-slot per edge).
//  - records bulk-staged to LDS (coalesced), compute reads qa via b128 and
//    the e-halves via b64 (wave-uniform broadcasts)
//  - sender nf rows bulk-staged to LDS, 4 lanes/row; snd index read directly
//    from GLOBAL recs (not the freshly written LDS) to break the intra-chunk
//    global->LDS->read->global serial chain
//  - per-edge LDS reads: b128 + b64 + 2x b32 (both conflict-free) vs v10's
//    2x b128 + 4x b32 (4-way conflicts on the type2 triple reads)
//  - once-per-node LDS scratch epilogue merges type2 triples (from v11)
//
// Record (32 B): uint4 A = h[0..7] as 4x half2 ; uint4 B = {e0|e1x, e1y|e1z,
// snd, 0}. h = swish(r@w1)/sqrt(32); 1/sqrt(3) folded into per-lane w2 col.
//
// product table (112 products -> out[96]):
//  slot0 (64 lanes):
//   lanes  0..7 : out[c]=lane      k=lane    i=lane    f=1        (s*w)
//   lanes  8..15: out[c]=lane      k=lane    i=lane-8  f=e0       (s*e0*w)
//   lanes 16..39: t=lane-16, m=t/3, x=t%3 -> partial of out[16+m]:
//                 k=16+m (w*1/sqrt3) i=8+t   f=e1[x]   (dot(v,e1) terms)
//   lanes 40..63: t=lane-40 -> out[24+t]    k=24+t/3 i=8+t f=1    (v*w)
//  slot1 (48 lanes used):
//   lanes  0..23: t=lane, m=t/3, x=t%3 -> out[48+t] k=32+m i=m f=e1[x]
//   lanes 24..47: t=lane-24 -> out[72+t]   k=40+t/3 i=8+t   f=e0
//   lanes 48..63: dead (w cols zeroed)

#define CAPACITY 96
#define CH 16   // records staged per chunk

typedef _Float16 half2v __attribute__((ext_vector_type(2)));

__device__ __forceinline__ unsigned pk16(float a, float b) {
    return __builtin_bit_cast(unsigned, __builtin_amdgcn_cvt_pkrtz(a, b));
}

__device__ __forceinline__ float dot2h(unsigned a, half2v b, float c) {
#if __has_builtin(__builtin_amdgcn_fdot2)
    return __builtin_amdgcn_fdot2(__builtin_bit_cast(half2v, a), b, c, false);
#else
    half2v av = __builtin_bit_cast(half2v, a);
    return fmaf((float)av.x, (float)b.x, fmaf((float)av.y, (float)b.y, c));
#endif
}

__global__ __launch_bounds__(256) void hist_kernel(
    const int* __restrict__ recv, int* __restrict__ cnt, int E)
{
    int e = blockIdx.x * 256 + threadIdx.x;
    if (e < E) atomicAdd(&cnt[recv[e]], 1);
}

__global__ __launch_bounds__(1024) void scan_kernel(
    const int* __restrict__ cnt, int* __restrict__ off,
    int* __restrict__ cursor, int N)
{
    __shared__ int lds[1024];
    const int t = threadIdx.x;
    const int CHN = (N + 1023) / 1024;
    const int lo = t * CHN;
    const int hi = min(N, lo + CHN);
    int s = 0;
    for (int i = lo; i < hi; ++i) s += cnt[i];
    lds[t] = s;
    __syncthreads();
    for (int d = 1; d < 1024; d <<= 1) {
        int v = (t >= d) ? lds[t - d] : 0;
        __syncthreads();
        lds[t] += v;
        __syncthreads();
    }
    int run = (t > 0) ? lds[t - 1] : 0;
    for (int i = lo; i < hi; ++i) {
        off[i] = run;
        cursor[i] = run;
        run += cnt[i];
    }
    if (t == 1023) off[N] = lds[1023];
}

// Edge-parallel: radial MLP, pack 32-B f16 record, place at bucket/sorted slot.
__global__ __launch_bounds__(256) void build_recs_kernel(
    const float* __restrict__ edge_features, // E x 4
    const float* __restrict__ radial,        // E x 8
    const float* __restrict__ w1g,           // 8 x 8
    const int* __restrict__ senders,
    const int* __restrict__ recv,
    int* __restrict__ slots,                 // cnt (bucket) or cursor (sorted)
    uint4* __restrict__ recs,                // 2 x uint4 per record
    int E, int CAP)
{
    __shared__ float sw1[64];
    for (int i = threadIdx.x; i < 64; i += 256) sw1[i] = w1g[i];
    __syncthreads();

    int e = blockIdx.x * 256 + threadIdx.x;
    if (e >= E) return;

    const int rcv_ = recv[e];
    // atomic first: overlap its latency with the MLP
    size_t addr;
    if (CAP > 0) {
        int slot = atomicAdd(&slots[rcv_], 1);
        slot = min(slot, CAP - 1); // safety clamp (P(deg>96) ~ 1e-18/node)
        addr = (size_t)rcv_ * CAP + slot;
    } else {
        addr = (size_t)atomicAdd(&slots[rcv_], 1);
    }

    const float4 ef = reinterpret_cast<const float4*>(edge_features)[e];
    const float4 ra = reinterpret_cast<const float4*>(radial)[2 * e + 0];
    const float4 rb = reinterpret_cast<const float4*>(radial)[2 * e + 1];
    const int snd = senders[e];

    float r[8] = {ra.x, ra.y, ra.z, ra.w, rb.x, rb.y, rb.z, rb.w};
    float h[8];
#pragma unroll
    for (int j = 0; j < 8; ++j) {
        float x = 0.f;
#pragma unroll
        for (int i = 0; i < 8; ++i) x = fmaf(r[i], sw1[i * 8 + j], x);
        // swish with 1/sqrt(32) folded
        h[j] = 0.17677669529663687f * x * __builtin_amdgcn_rcpf(1.0f + __expf(-x));
    }

    uint4 qa, qb;
    qa.x = pk16(h[0], h[1]); qa.y = pk16(h[2], h[3]);
    qa.z = pk16(h[4], h[5]); qa.w = pk16(h[6], h[7]);
    qb.x = pk16(ef.x, ef.y); qb.y = pk16(ef.z, ef.w);
    qb.z = (unsigned)snd;    qb.w = 0u;
    recs[2 * addr + 0] = qa;
    recs[2 * addr + 1] = qb;
}

// One wave per node, 4 nodes/block, no barriers (wave-private LDS regions).
template<bool CAPMODE>
__global__ __launch_bounds__(256) void node_v12_kernel(
    const float* __restrict__ node_feats,    // N x 32
    const float* __restrict__ w2g,           // 8 x 48
    const int* __restrict__ off,             // cnt[N] (CAPMODE) or off[N+1]
    const uint4* __restrict__ recs,
    float* __restrict__ out,                 // N x 96
    int N)
{
    const int lane = threadIdx.x & 63;
    const int wv   = threadIdx.x >> 6;   // 0..3 = local node
    const int node = blockIdx.x * 4 + wv;

    __shared__ uint4 rec_lds[4][CH][2];      // 2 KB
    __shared__ float nf_lds[4][CH][32];      // 8 KB
    __shared__ float scr[4][128];            // 2 KB epilogue scratch

    // ---- per-lane product-slot tables (all loop-invariant) ----
    int kA, iA, selA; float scA = 1.0f;
    if (lane < 8)       { kA = lane;         iA = lane;     selA = 0; }
    else if (lane < 16) { kA = lane;         iA = lane - 8; selA = 1; }
    else if (lane < 40) { int t = lane - 16; kA = 16 + t / 3; iA = 8 + t;
                          selA = 2 + t % 3;  scA = 0.57735026918962576f; }
    else                { int t = lane - 40; kA = 24 + t / 3; iA = 8 + t; selA = 0; }

    int kB, iB, selB; const bool deadB = (lane >= 48);
    if (lane < 24)      { int t = lane;      kB = 32 + t / 3; iB = t / 3; selB = 2 + t % 3; }
    else if (lane < 48) { int t = lane - 24; kB = 40 + t / 3; iB = 8 + t; selB = 1; }
    else                { kB = 0; iB = 0; selB = 0; }

    half2v wpA[4], wpB[4];
#pragma unroll
    for (int i = 0; i < 4; ++i) {
        wpA[i].x = (_Float16)(w2g[(2 * i + 0) * 48 + kA] * scA);
        wpA[i].y = (_Float16)(w2g[(2 * i + 1) * 48 + kA] * scA);
        wpB[i].x = deadB ? (_Float16)0.f : (_Float16)(w2g[(2 * i + 0) * 48 + kB]);
        wpB[i].y = deadB ? (_Float16)0.f : (_Float16)(w2g[(2 * i + 1) * 48 + kB]);
    }

    if (node >= N) return;  // safe: no __syncthreads in this kernel

    int base, count;
    if (CAPMODE) { base = node * CAPACITY; count = min(off[node], CAPACITY); }
    else         { base = off[node];       count = off[node + 1] - base; }
    const uint4* rp = recs + (size_t)base * 2;

    const int r_stage = lane >> 2;       // 0..15: which record's nf row I stage
    const int q_stage = lane & 3;        // 0..3: which quarter of the row

    float acc0 = 0.f, acc1 = 0.f;

    for (int c0i = 0; c0i < count; c0i += CH) {
        const int cc = min(CH, count - c0i);

        // ---- stage records: lanes 0..2*cc-1, fully coalesced ----
        if (lane < 2 * cc)
            rec_lds[wv][lane >> 1][lane & 1] = rp[(size_t)c0i * 2 + lane];

        // ---- stage sender nf rows: 4 lanes per record ----
        // snd read straight from GLOBAL recs (qb.z = dword 6 of record) so the
        // nf gather does not wait on the rec->LDS round trip above.
        if (r_stage < cc) {
            const unsigned snd =
                reinterpret_cast<const unsigned*>(rp)[((size_t)c0i + r_stage) * 8 + 6];
            const float4* src = reinterpret_cast<const float4*>(node_feats)
                                + (size_t)snd * 8 + q_stage * 2;
            const float4 v0 = src[0];
            const float4 v1 = src[1];
            float4* dst = reinterpret_cast<float4*>(&nf_lds[wv][r_stage][q_stage * 8]);
            dst[0] = v0;
            dst[1] = v1;
        }

        // ---- pure LDS + VALU compute (same-wave data: auto lgkm waits) ----
#pragma unroll 4
        for (int i = 0; i < cc; ++i) {
            const uint4 qa = rec_lds[wv][i][0];
            const uint2 eq = *reinterpret_cast<const uint2*>(&rec_lds[wv][i][1]);

            float wAv = dot2h(qa.x, wpA[0], 0.f);
            wAv = dot2h(qa.y, wpA[1], wAv);
            wAv = dot2h(qa.z, wpA[2], wAv);
            wAv = dot2h(qa.w, wpA[3], wAv);
            float wBv = dot2h(qa.x, wpB[0], 0.f);
            wBv = dot2h(qa.y, wpB[1], wBv);
            wBv = dot2h(qa.z, wpB[2], wBv);
            wBv = dot2h(qa.w, wpB[3], wBv);

            const half2v eA = __builtin_bit_cast(half2v, eq.x);
            const half2v eB = __builtin_bit_cast(half2v, eq.y);
            const float e0  = (float)eA.x, e1x = (float)eA.y;
            const float e1y = (float)eB.x, e1z = (float)eB.y;

            const float n0 = nf_lds[wv][i][iA];   // 2-way/broadcast, conflict-free
            const float n1 = nf_lds[wv][i][iB];   // broadcast groups, conflict-free

            const float fA = (selA == 0) ? 1.0f
                           : (selA == 1) ? e0
                           : (selA == 2) ? e1x
                           : (selA == 3) ? e1y : e1z;
            const float fB = (selB == 1) ? e0
                           : (selB == 2) ? e1x
                           : (selB == 3) ? e1y : e1z;

            acc0 = fmaf(wAv, n0 * fA, acc0);
            acc1 = fmaf(wBv, n1 * fB, acc1);
        }
    }

    // ---- epilogue: merge type2 triples, permute to output layout ----
    scr[wv][lane]      = acc0;
    scr[wv][64 + lane] = acc1;
    // same-wave LDS: no barrier needed, compiler inserts lgkmcnt waits
    float o0;
    if (lane < 16) {
        o0 = scr[wv][lane];
    } else if (lane < 24) {
        const int t = 16 + 3 * (lane - 16);
        o0 = scr[wv][t] + scr[wv][t + 1] + scr[wv][t + 2];
    } else {
        o0 = scr[wv][lane + 16];   // comps 24..47 <- slot0[40+..]; 48..63 <- slot1[0..15]
    }
    float* orow = out + (size_t)node * 96;
    orow[lane] = o0;
    if (lane < 32) orow[64 + lane] = scr[wv][80 + lane];  // comps 64..95 <- slot1[16..47]
}

extern "C" void kernel_launch(void* const* d_in, const int* in_sizes, int n_in,
                              void* d_out, int out_size, void* d_ws, size_t ws_size,
                              hipStream_t stream) {
    const float* node_feats    = (const float*)d_in[0];
    const float* edge_features = (const float*)d_in[1];
    const float* radial        = (const float*)d_in[2];
    const float* w1            = (const float*)d_in[3];
    const float* w2            = (const float*)d_in[4];
    const int*   senders       = (const int*)d_in[5];
    const int*   receivers     = (const int*)d_in[6];
    float* out = (float*)d_out;

    const int E = in_sizes[5];
    const int N = out_size / 96;
    const int eblocks = (E + 255) / 256;
    const int nblocks = (N + 3) / 4;   // 4 nodes/block, 1 wave/node

    const size_t needP1 = (size_t)N * CAPACITY * 32 + (size_t)N * sizeof(int);

    if (ws_size >= needP1) {
        // P1 (best known): capacity buckets. layout: recs[N*CAP*32 B] | cnt[N]
        uint4* recs = (uint4*)d_ws;
        int* cnt = (int*)((char*)d_ws + (size_t)N * CAPACITY * 32);

        (void)hipMemsetAsync(cnt, 0, (size_t)N * sizeof(int), stream);
        hipLaunchKernelGGL(build_recs_kernel, dim3(eblocks), dim3(256), 0, stream,
                           edge_features, radial, w1, senders, receivers,
                           cnt, recs, E, CAPACITY);
        hipLaunchKernelGGL(node_v12_kernel<true>, dim3(nblocks), dim3(256), 0, stream,
                           node_feats, w2, cnt, recs, out, N);
    } else {
        // P2 fallback: counting sort. layout: recs[E*32] | cnt[N] | off[N+1] | cursor[N]
        uint4* recs = (uint4*)d_ws;
        int* cnt    = (int*)((char*)d_ws + (size_t)E * 32);
        int* off    = cnt + N;
        int* cursor = cnt + 2 * N + 1;

        (void)hipMemsetAsync(cnt, 0, (size_t)N * sizeof(int), stream);
        hipLaunchKernelGGL(hist_kernel, dim3(eblocks), dim3(256), 0, stream,
                           receivers, cnt, E);
        hipLaunchKernelGGL(scan_kernel, dim3(1), dim3(1024), 0, stream,
                           cnt, off, cursor, N);
        hipLaunchKernelGGL(build_recs_kernel, dim3(eblocks), dim3(256), 0, stream,
                           edge_features, radial, w1, senders, receivers,
                           cursor, recs, E, 0);
        hipLaunchKernelGGL(node_v12_kernel<false>, dim3(nblocks), dim3(256), 0, stream,
                           node_feats, w2, off, recs, out, N);
    }
}

// Round 4
// 308.040 us; speedup vs baseline: 1.1752x; 1.0554x over previous
//
#include <hip/hip_runtime.h>

// MessagePassingConvolution, round 14.
// Base = v12 (proven correct, 137.9us node). Two provable changes only:
//  1. fdot2 one-hot-mask edge-factor selection: build packs
//     qb = {pk(1,e0), pk(e1x,e1y), snd, pk(e1z,0)}; compute does
//     fA = fdot2(qb.x,mA0)+fdot2(qb.y,mA1)+fdot2(qb.w,mA2) with per-lane
//     loop-invariant one-hot masks. Removes 4 cvt + ~14 select insts/edge.
//  2. nf_lds row stride 32->36 floats: staging ds_write_b128 start banks
//     (4r+8q)%32 spread uniformly -> 8 accesses/bank = conflict floor
//     (was 16/bank-group at stride 32). Reads unaffected.
// Plus the build-side probe kept from r13: cnt counters padded to one per
// 64B line (stride 16 ints) to test atomic line-contention.
// v13's register pipeline / upfront shfl gather is QUARANTINED (order-
// dependent divergence under graph replay, root cause not proven).
//
// Record (32 B): uint4 A = h[0..7] as 4x half2 ;
//                uint4 B = {1|e0, e1x|e1y, snd, e1z|0}.
// h = swish(r@w1)/sqrt(32); 1/sqrt(3) folded into per-lane w2 col.
//
// product table (112 products -> out[96]):
//  slot0 (64 lanes):
//   lanes  0..7 : out[c]=lane      k=lane    i=lane    f=1        (s*w)
//   lanes  8..15: out[c]=lane      k=lane    i=lane-8  f=e0       (s*e0*w)
//   lanes 16..39: t=lane-16, m=t/3, x=t%3 -> partial of out[16+m]:
//                 k=16+m (w*1/sqrt3) i=8+t   f=e1[x]   (dot(v,e1) terms)
//   lanes 40..63: t=lane-40 -> out[24+t]    k=24+t/3 i=8+t f=1    (v*w)
//  slot1 (48 lanes used):
//   lanes  0..23: t=lane, m=t/3, x=t%3 -> out[48+t] k=32+m i=m f=e1[x]
//   lanes 24..47: t=lane-24 -> out[72+t]   k=40+t/3 i=8+t   f=e0
//   lanes 48..63: dead (w cols zeroed)

#define CAPACITY 96
#define CH 16   // records staged per chunk

typedef _Float16 half2v __attribute__((ext_vector_type(2)));

__device__ __forceinline__ unsigned pk16(float a, float b) {
    return __builtin_bit_cast(unsigned, __builtin_amdgcn_cvt_pkrtz(a, b));
}

__device__ __forceinline__ float dot2h(unsigned a, half2v b, float c) {
#if __has_builtin(__builtin_amdgcn_fdot2)
    return __builtin_amdgcn_fdot2(__builtin_bit_cast(half2v, a), b, c, false);
#else
    half2v av = __builtin_bit_cast(half2v, a);
    return fmaf((float)av.x, (float)b.x, fmaf((float)av.y, (float)b.y, c));
#endif
}

__global__ __launch_bounds__(256) void hist_kernel(
    const int* __restrict__ recv, int* __restrict__ cnt, int E)
{
    int e = blockIdx.x * 256 + threadIdx.x;
    if (e < E) atomicAdd(&cnt[recv[e]], 1);
}

__global__ __launch_bounds__(1024) void scan_kernel(
    const int* __restrict__ cnt, int* __restrict__ off,
    int* __restrict__ cursor, int N)
{
    __shared__ int lds[1024];
    const int t = threadIdx.x;
    const int CHN = (N + 1023) / 1024;
    const int lo = t * CHN;
    const int hi = min(N, lo + CHN);
    int s = 0;
    for (int i = lo; i < hi; ++i) s += cnt[i];
    lds[t] = s;
    __syncthreads();
    for (int d = 1; d < 1024; d <<= 1) {
        int v = (t >= d) ? lds[t - d] : 0;
        __syncthreads();
        lds[t] += v;
        __syncthreads();
    }
    int run = (t > 0) ? lds[t - 1] : 0;
    for (int i = lo; i < hi; ++i) {
        off[i] = run;
        cursor[i] = run;
        run += cnt[i];
    }
    if (t == 1023) off[N] = lds[1023];
}

// Edge-parallel: radial MLP, pack 32-B f16 record, place at bucket/sorted slot.
__global__ __launch_bounds__(256) void build_recs_kernel(
    const float* __restrict__ edge_features, // E x 4
    const float* __restrict__ radial,        // E x 8
    const float* __restrict__ w1g,           // 8 x 8
    const int* __restrict__ senders,
    const int* __restrict__ recv,
    int* __restrict__ slots,                 // cnt (bucket) or cursor (sorted)
    uint4* __restrict__ recs,                // 2 x uint4 per record
    int E, int CAP, int cstr)
{
    __shared__ float sw1[64];
    for (int i = threadIdx.x; i < 64; i += 256) sw1[i] = w1g[i];
    __syncthreads();

    int e = blockIdx.x * 256 + threadIdx.x;
    if (e >= E) return;

    const int rcv_ = recv[e];
    // atomic first: overlap its latency with the MLP
    size_t addr;
    if (CAP > 0) {
        int slot = atomicAdd(&slots[(size_t)rcv_ * cstr], 1);
        slot = min(slot, CAP - 1); // safety clamp (P(deg>96) ~ 1e-18/node)
        addr = (size_t)rcv_ * CAP + slot;
    } else {
        addr = (size_t)atomicAdd(&slots[rcv_], 1);
    }

    const float4 ef = reinterpret_cast<const float4*>(edge_features)[e];
    const float4 ra = reinterpret_cast<const float4*>(radial)[2 * e + 0];
    const float4 rb = reinterpret_cast<const float4*>(radial)[2 * e + 1];
    const int snd = senders[e];

    float r[8] = {ra.x, ra.y, ra.z, ra.w, rb.x, rb.y, rb.z, rb.w};
    float h[8];
#pragma unroll
    for (int j = 0; j < 8; ++j) {
        float x = 0.f;
#pragma unroll
        for (int i = 0; i < 8; ++i) x = fmaf(r[i], sw1[i * 8 + j], x);
        // swish with 1/sqrt(32) folded
        h[j] = 0.17677669529663687f * x * __builtin_amdgcn_rcpf(1.0f + __expf(-x));
    }

    uint4 qa, qb;
    qa.x = pk16(h[0], h[1]); qa.y = pk16(h[2], h[3]);
    qa.z = pk16(h[4], h[5]); qa.w = pk16(h[6], h[7]);
    qb.x = pk16(1.0f, ef.x);     // (1, e0)
    qb.y = pk16(ef.y, ef.z);     // (e1x, e1y)
    qb.z = (unsigned)snd;
    qb.w = pk16(ef.w, 0.0f);     // (e1z, 0)
    recs[2 * addr + 0] = qa;
    recs[2 * addr + 1] = qb;
}

// One wave per node, 4 nodes/block, no barriers (wave-private LDS regions).
// CSTR: stride (ints) between cnt counters (CAPMODE only).
template<bool CAPMODE, int CSTR>
__global__ __launch_bounds__(256) void node_v14_kernel(
    const float* __restrict__ node_feats,    // N x 32
    const float* __restrict__ w2g,           // 8 x 48
    const int* __restrict__ off,             // cnt[N*CSTR] (CAPMODE) or off[N+1]
    const uint4* __restrict__ recs,
    float* __restrict__ out,                 // N x 96
    int N)
{
    const int lane = threadIdx.x & 63;
    const int wv   = threadIdx.x >> 6;   // 0..3 = local node
    const int node = blockIdx.x * 4 + wv;

    __shared__ uint4 rec_lds[4][CH][2];      // 2 KB
    __shared__ float nf_lds[4][CH][36];      // 9 KB (36: bank-balanced writes)
    __shared__ float scr[4][128];            // 2 KB epilogue scratch

    // ---- per-lane product-slot tables (all loop-invariant) ----
    int kA, iA, selA; float scA = 1.0f;
    if (lane < 8)       { kA = lane;         iA = lane;     selA = 0; }
    else if (lane < 16) { kA = lane;         iA = lane - 8; selA = 1; }
    else if (lane < 40) { int t = lane - 16; kA = 16 + t / 3; iA = 8 + t;
                          selA = 2 + t % 3;  scA = 0.57735026918962576f; }
    else                { int t = lane - 40; kA = 24 + t / 3; iA = 8 + t; selA = 0; }

    int kB, iB, selB; const bool deadB = (lane >= 48);
    if (lane < 24)      { int t = lane;      kB = 32 + t / 3; iB = t / 3; selB = 2 + t % 3; }
    else if (lane < 48) { int t = lane - 24; kB = 40 + t / 3; iB = 8 + t; selB = 1; }
    else                { kB = 0; iB = 0; selB = 0; }

    // one-hot f16 masks: f = fdot2(qb.x, m0) + fdot2(qb.y, m1) + fdot2(qb.w, m2)
    // qb.x=(1,e0) qb.y=(e1x,e1y) qb.w=(e1z,0); sel: 0->1, 1->e0, 2..4->e1xyz
    half2v mA0 = {0, 0}, mA1 = {0, 0}, mA2 = {0, 0};
    if      (selA == 0) mA0.x = (_Float16)1.f;
    else if (selA == 1) mA0.y = (_Float16)1.f;
    else if (selA == 2) mA1.x = (_Float16)1.f;
    else if (selA == 3) mA1.y = (_Float16)1.f;
    else                mA2.x = (_Float16)1.f;
    half2v mB0 = {0, 0}, mB1 = {0, 0}, mB2 = {0, 0};
    if (!deadB) {
        if      (selB == 1) mB0.y = (_Float16)1.f;
        else if (selB == 2) mB1.x = (_Float16)1.f;
        else if (selB == 3) mB1.y = (_Float16)1.f;
        else                mB2.x = (_Float16)1.f;
    }

    half2v wpA[4], wpB[4];
#pragma unroll
    for (int i = 0; i < 4; ++i) {
        wpA[i].x = (_Float16)(w2g[(2 * i + 0) * 48 + kA] * scA);
        wpA[i].y = (_Float16)(w2g[(2 * i + 1) * 48 + kA] * scA);
        wpB[i].x = deadB ? (_Float16)0.f : (_Float16)(w2g[(2 * i + 0) * 48 + kB]);
        wpB[i].y = deadB ? (_Float16)0.f : (_Float16)(w2g[(2 * i + 1) * 48 + kB]);
    }

    if (node >= N) return;  // safe: no __syncthreads in this kernel

    int base, count;
    if (CAPMODE) { base = node * CAPACITY; count = min(off[(size_t)node * CSTR], CAPACITY); }
    else         { base = off[node];       count = off[node + 1] - base; }
    const uint4* rp = recs + (size_t)base * 2;

    const int r_stage = lane >> 2;       // 0..15: which record's nf row I stage
    const int q_stage = lane & 3;        // 0..3: which quarter of the row

    float acc0 = 0.f, acc1 = 0.f;

    for (int c0i = 0; c0i < count; c0i += CH) {
        const int cc = min(CH, count - c0i);

        // ---- stage records: lanes 0..2*cc-1, fully coalesced ----
        if (lane < 2 * cc)
            rec_lds[wv][lane >> 1][lane & 1] = rp[(size_t)c0i * 2 + lane];

        // ---- stage sender nf rows: 4 lanes per record ----
        // snd read straight from GLOBAL recs (qb.z = dword 6 of record) so the
        // nf gather does not wait on the rec->LDS round trip above.
        if (r_stage < cc) {
            const unsigned snd =
                reinterpret_cast<const unsigned*>(rp)[((size_t)c0i + r_stage) * 8 + 6];
            const float4* src = reinterpret_cast<const float4*>(node_feats)
                                + (size_t)snd * 8 + q_stage * 2;
            const float4 v0 = src[0];
            const float4 v1 = src[1];
            float* dst = &nf_lds[wv][r_stage][q_stage * 8];
            *reinterpret_cast<float4*>(dst)     = v0;
            *reinterpret_cast<float4*>(dst + 4) = v1;
        }

        // ---- pure LDS + VALU compute (same-wave data: auto lgkm waits) ----
#pragma unroll 4
        for (int i = 0; i < cc; ++i) {
            const uint4 qa = rec_lds[wv][i][0];   // wave-uniform broadcast
            const uint4 qb = rec_lds[wv][i][1];   // wave-uniform broadcast

            float wAv = dot2h(qa.x, wpA[0], 0.f);
            wAv = dot2h(qa.y, wpA[1], wAv);
            wAv = dot2h(qa.z, wpA[2], wAv);
            wAv = dot2h(qa.w, wpA[3], wAv);
            float wBv = dot2h(qa.x, wpB[0], 0.f);
            wBv = dot2h(qa.y, wpB[1], wBv);
            wBv = dot2h(qa.z, wpB[2], wBv);
            wBv = dot2h(qa.w, wpB[3], wBv);

            // edge factor via one-hot fdot2 (no cvt, no selects)
            float fA = dot2h(qb.x, mA0, 0.f);
            fA = dot2h(qb.y, mA1, fA);
            fA = dot2h(qb.w, mA2, fA);
            float fB = dot2h(qb.x, mB0, 0.f);
            fB = dot2h(qb.y, mB1, fB);
            fB = dot2h(qb.w, mB2, fB);

            const float n0 = nf_lds[wv][i][iA];   // conflict-free
            const float n1 = nf_lds[wv][i][iB];   // broadcast groups

            acc0 = fmaf(wAv, n0 * fA, acc0);
            acc1 = fmaf(wBv, n1 * fB, acc1);
        }
    }

    // ---- epilogue: merge type2 triples, permute to output layout ----
    scr[wv][lane]      = acc0;
    scr[wv][64 + lane] = acc1;
    // same-wave LDS: no barrier needed, compiler inserts lgkmcnt waits
    float o0;
    if (lane < 16) {
        o0 = scr[wv][lane];
    } else if (lane < 24) {
        const int t = 16 + 3 * (lane - 16);
        o0 = scr[wv][t] + scr[wv][t + 1] + scr[wv][t + 2];
    } else {
        o0 = scr[wv][lane + 16];   // comps 24..47 <- slot0[40+..]; 48..63 <- slot1[0..15]
    }
    float* orow = out + (size_t)node * 96;
    orow[lane] = o0;
    if (lane < 32) orow[64 + lane] = scr[wv][80 + lane];  // comps 64..95 <- slot1[16..47]
}

extern "C" void kernel_launch(void* const* d_in, const int* in_sizes, int n_in,
                              void* d_out, int out_size, void* d_ws, size_t ws_size,
                              hipStream_t stream) {
    const float* node_feats    = (const float*)d_in[0];
    const float* edge_features = (const float*)d_in[1];
    const float* radial        = (const float*)d_in[2];
    const float* w1            = (const float*)d_in[3];
    const float* w2            = (const float*)d_in[4];
    const int*   senders       = (const int*)d_in[5];
    const int*   receivers     = (const int*)d_in[6];
    float* out = (float*)d_out;

    const int E = in_sizes[5];
    const int N = out_size / 96;
    const int eblocks = (E + 255) / 256;
    const int nblocks = (N + 3) / 4;   // 4 nodes/block, 1 wave/node

    const size_t recsBytes = (size_t)N * CAPACITY * 32;
    const size_t needPad   = recsBytes + (size_t)N * 16 * sizeof(int);
    const size_t needP1    = recsBytes + (size_t)N * sizeof(int);

    if (ws_size >= needPad) {
        // P1 + padded counters (1 per 64B line): test atomic line-contention
        uint4* recs = (uint4*)d_ws;
        int* cnt = (int*)((char*)d_ws + recsBytes);

        (void)hipMemsetAsync(cnt, 0, (size_t)N * 16 * sizeof(int), stream);
        hipLaunchKernelGGL(build_recs_kernel, dim3(eblocks), dim3(256), 0, stream,
                           edge_features, radial, w1, senders, receivers,
                           cnt, recs, E, CAPACITY, 16);
        hipLaunchKernelGGL((node_v14_kernel<true, 16>), dim3(nblocks), dim3(256), 0, stream,
                           node_feats, w2, cnt, recs, out, N);
    } else if (ws_size >= needP1) {
        // P1 unpadded
        uint4* recs = (uint4*)d_ws;
        int* cnt = (int*)((char*)d_ws + recsBytes);

        (void)hipMemsetAsync(cnt, 0, (size_t)N * sizeof(int), stream);
        hipLaunchKernelGGL(build_recs_kernel, dim3(eblocks), dim3(256), 0, stream,
                           edge_features, radial, w1, senders, receivers,
                           cnt, recs, E, CAPACITY, 1);
        hipLaunchKernelGGL((node_v14_kernel<true, 1>), dim3(nblocks), dim3(256), 0, stream,
                           node_feats, w2, cnt, recs, out, N);
    } else {
        // P2 fallback: counting sort. layout: recs[E*32] | cnt[N] | off[N+1] | cursor[N]
        uint4* recs = (uint4*)d_ws;
        int* cnt    = (int*)((char*)d_ws + (size_t)E * 32);
        int* off    = cnt + N;
        int* cursor = cnt + 2 * N + 1;

        (void)hipMemsetAsync(cnt, 0, (size_t)N * sizeof(int), stream);
        hipLaunchKernelGGL(hist_kernel, dim3(eblocks), dim3(256), 0, stream,
                           receivers, cnt, E);
        hipLaunchKernelGGL(scan_kernel, dim3(1), dim3(1024), 0, stream,
                           cnt, off, cursor, N);
        hipLaunchKernelGGL(build_recs_kernel, dim3(eblocks), dim3(256), 0, stream,
                           edge_features, radial, w1, senders, receivers,
                           cursor, recs, E, 0, 1);
        hipLaunchKernelGGL((node_v14_kernel<false, 1>), dim3(nblocks), dim3(256), 0, stream,
                           node_feats, w2, off, recs, out, N);
    }
}

// Round 5
// 286.407 us; speedup vs baseline: 1.2640x; 1.0755x over previous
//
#include <hip/hip_runtime.h>

// MessagePassingConvolution, round 15.
// Base = v14 (proven: 120us node, 0 bank conflicts). ONE change:
//  - rec_lds deleted. qa/qb are wave-uniform (every lane reads the same
//    record) -> read straight from GLOBAL at a readfirstlane'd base.
//    const __restrict__ + uniform address => compiler emits s_load through
//    the scalar cache, which costs the (per-CU, shared) LDS pipe ZERO.
//    v14 inner loop paid ~38 LDS-pipe cy/edge (2x b128 broadcast + 2x b32);
//    6250 edges/CU x 38cy = 99us = the measured 120us. v15 pays ~13 cy/edge.
//  - nf staging unchanged (chunked gather, stride-36 bank-balanced, snd
//    read from global recs as in v14). Correct by construction.
//
// Record (32 B): uint4 A = h[0..7] as 4x half2 ;
//                uint4 B = {1|e0, e1x|e1y, snd, e1z|0}.
// h = swish(r@w1)/sqrt(32); 1/sqrt(3) folded into per-lane w2 col.
//
// product table (112 products -> out[96]):
//  slot0 (64 lanes):
//   lanes  0..7 : out[c]=lane      k=lane    i=lane    f=1        (s*w)
//   lanes  8..15: out[c]=lane      k=lane    i=lane-8  f=e0       (s*e0*w)
//   lanes 16..39: t=lane-16, m=t/3, x=t%3 -> partial of out[16+m]:
//                 k=16+m (w*1/sqrt3) i=8+t   f=e1[x]   (dot(v,e1) terms)
//   lanes 40..63: t=lane-40 -> out[24+t]    k=24+t/3 i=8+t f=1    (v*w)
//  slot1 (48 lanes used):
//   lanes  0..23: t=lane, m=t/3, x=t%3 -> out[48+t] k=32+m i=m f=e1[x]
//   lanes 24..47: t=lane-24 -> out[72+t]   k=40+t/3 i=8+t   f=e0
//   lanes 48..63: dead (w cols zeroed)

#define CAPACITY 96
#define CH 16   // records staged per chunk

typedef _Float16 half2v __attribute__((ext_vector_type(2)));

__device__ __forceinline__ unsigned pk16(float a, float b) {
    return __builtin_bit_cast(unsigned, __builtin_amdgcn_cvt_pkrtz(a, b));
}

__device__ __forceinline__ float dot2h(unsigned a, half2v b, float c) {
#if __has_builtin(__builtin_amdgcn_fdot2)
    return __builtin_amdgcn_fdot2(__builtin_bit_cast(half2v, a), b, c, false);
#else
    half2v av = __builtin_bit_cast(half2v, a);
    return fmaf((float)av.x, (float)b.x, fmaf((float)av.y, (float)b.y, c));
#endif
}

__global__ __launch_bounds__(256) void hist_kernel(
    const int* __restrict__ recv, int* __restrict__ cnt, int E)
{
    int e = blockIdx.x * 256 + threadIdx.x;
    if (e < E) atomicAdd(&cnt[recv[e]], 1);
}

__global__ __launch_bounds__(1024) void scan_kernel(
    const int* __restrict__ cnt, int* __restrict__ off,
    int* __restrict__ cursor, int N)
{
    __shared__ int lds[1024];
    const int t = threadIdx.x;
    const int CHN = (N + 1023) / 1024;
    const int lo = t * CHN;
    const int hi = min(N, lo + CHN);
    int s = 0;
    for (int i = lo; i < hi; ++i) s += cnt[i];
    lds[t] = s;
    __syncthreads();
    for (int d = 1; d < 1024; d <<= 1) {
        int v = (t >= d) ? lds[t - d] : 0;
        __syncthreads();
        lds[t] += v;
        __syncthreads();
    }
    int run = (t > 0) ? lds[t - 1] : 0;
    for (int i = lo; i < hi; ++i) {
        off[i] = run;
        cursor[i] = run;
        run += cnt[i];
    }
    if (t == 1023) off[N] = lds[1023];
}

// Edge-parallel: radial MLP, pack 32-B f16 record, place at bucket/sorted slot.
__global__ __launch_bounds__(256) void build_recs_kernel(
    const float* __restrict__ edge_features, // E x 4
    const float* __restrict__ radial,        // E x 8
    const float* __restrict__ w1g,           // 8 x 8
    const int* __restrict__ senders,
    const int* __restrict__ recv,
    int* __restrict__ slots,                 // cnt (bucket) or cursor (sorted)
    uint4* __restrict__ recs,                // 2 x uint4 per record
    int E, int CAP, int cstr)
{
    __shared__ float sw1[64];
    for (int i = threadIdx.x; i < 64; i += 256) sw1[i] = w1g[i];
    __syncthreads();

    int e = blockIdx.x * 256 + threadIdx.x;
    if (e >= E) return;

    const int rcv_ = recv[e];
    // atomic first: overlap its latency with the MLP
    size_t addr;
    if (CAP > 0) {
        int slot = atomicAdd(&slots[(size_t)rcv_ * cstr], 1);
        slot = min(slot, CAP - 1); // safety clamp (P(deg>96) ~ 1e-18/node)
        addr = (size_t)rcv_ * CAP + slot;
    } else {
        addr = (size_t)atomicAdd(&slots[rcv_], 1);
    }

    const float4 ef = reinterpret_cast<const float4*>(edge_features)[e];
    const float4 ra = reinterpret_cast<const float4*>(radial)[2 * e + 0];
    const float4 rb = reinterpret_cast<const float4*>(radial)[2 * e + 1];
    const int snd = senders[e];

    float r[8] = {ra.x, ra.y, ra.z, ra.w, rb.x, rb.y, rb.z, rb.w};
    float h[8];
#pragma unroll
    for (int j = 0; j < 8; ++j) {
        float x = 0.f;
#pragma unroll
        for (int i = 0; i < 8; ++i) x = fmaf(r[i], sw1[i * 8 + j], x);
        // swish with 1/sqrt(32) folded
        h[j] = 0.17677669529663687f * x * __builtin_amdgcn_rcpf(1.0f + __expf(-x));
    }

    uint4 qa, qb;
    qa.x = pk16(h[0], h[1]); qa.y = pk16(h[2], h[3]);
    qa.z = pk16(h[4], h[5]); qa.w = pk16(h[6], h[7]);
    qb.x = pk16(1.0f, ef.x);     // (1, e0)
    qb.y = pk16(ef.y, ef.z);     // (e1x, e1y)
    qb.z = (unsigned)snd;
    qb.w = pk16(ef.w, 0.0f);     // (e1z, 0)
    recs[2 * addr + 0] = qa;
    recs[2 * addr + 1] = qb;
}

// One wave per node, 4 nodes/block, no barriers (wave-private LDS regions).
// CSTR: stride (ints) between cnt counters (CAPMODE only).
template<bool CAPMODE, int CSTR>
__global__ __launch_bounds__(256) void node_v15_kernel(
    const float* __restrict__ node_feats,    // N x 32
    const float* __restrict__ w2g,           // 8 x 48
    const int* __restrict__ off,             // cnt[N*CSTR] (CAPMODE) or off[N+1]
    const uint4* __restrict__ recs,
    float* __restrict__ out,                 // N x 96
    int N)
{
    const int lane = threadIdx.x & 63;
    const int wv   = threadIdx.x >> 6;   // 0..3 = local node
    const int node = blockIdx.x * 4 + wv;

    __shared__ float nf_lds[4][CH][36];      // 9 KB (36: bank-balanced writes)
    __shared__ float scr[4][128];            // 2 KB epilogue scratch

    // ---- per-lane product-slot tables (all loop-invariant) ----
    int kA, iA, selA; float scA = 1.0f;
    if (lane < 8)       { kA = lane;         iA = lane;     selA = 0; }
    else if (lane < 16) { kA = lane;         iA = lane - 8; selA = 1; }
    else if (lane < 40) { int t = lane - 16; kA = 16 + t / 3; iA = 8 + t;
                          selA = 2 + t % 3;  scA = 0.57735026918962576f; }
    else                { int t = lane - 40; kA = 24 + t / 3; iA = 8 + t; selA = 0; }

    int kB, iB, selB; const bool deadB = (lane >= 48);
    if (lane < 24)      { int t = lane;      kB = 32 + t / 3; iB = t / 3; selB = 2 + t % 3; }
    else if (lane < 48) { int t = lane - 24; kB = 40 + t / 3; iB = 8 + t; selB = 1; }
    else                { kB = 0; iB = 0; selB = 0; }

    // one-hot f16 masks: f = fdot2(qb.x, m0) + fdot2(qb.y, m1) + fdot2(qb.w, m2)
    // qb.x=(1,e0) qb.y=(e1x,e1y) qb.w=(e1z,0); sel: 0->1, 1->e0, 2..4->e1xyz
    half2v mA0 = {0, 0}, mA1 = {0, 0}, mA2 = {0, 0};
    if      (selA == 0) mA0.x = (_Float16)1.f;
    else if (selA == 1) mA0.y = (_Float16)1.f;
    else if (selA == 2) mA1.x = (_Float16)1.f;
    else if (selA == 3) mA1.y = (_Float16)1.f;
    else                mA2.x = (_Float16)1.f;
    half2v mB0 = {0, 0}, mB1 = {0, 0}, mB2 = {0, 0};
    if (!deadB) {
        if      (selB == 1) mB0.y = (_Float16)1.f;
        else if (selB == 2) mB1.x = (_Float16)1.f;
        else if (selB == 3) mB1.y = (_Float16)1.f;
        else                mB2.x = (_Float16)1.f;
    }

    half2v wpA[4], wpB[4];
#pragma unroll
    for (int i = 0; i < 4; ++i) {
        wpA[i].x = (_Float16)(w2g[(2 * i + 0) * 48 + kA] * scA);
        wpA[i].y = (_Float16)(w2g[(2 * i + 1) * 48 + kA] * scA);
        wpB[i].x = deadB ? (_Float16)0.f : (_Float16)(w2g[(2 * i + 0) * 48 + kB]);
        wpB[i].y = deadB ? (_Float16)0.f : (_Float16)(w2g[(2 * i + 1) * 48 + kB]);
    }

    if (node >= N) return;  // safe: no __syncthreads in this kernel

    int base, count;
    if (CAPMODE) { base = node * CAPACITY; count = min(off[(size_t)node * CSTR], CAPACITY); }
    else         { base = off[node];       count = off[node + 1] - base; }
    // scalar-root: wave-uniform values into SGPRs so record reads become
    // s_load through the scalar cache (off the LDS/VALU pipes entirely)
    base  = __builtin_amdgcn_readfirstlane(base);
    count = __builtin_amdgcn_readfirstlane(count);
    const uint4* rp = recs + (size_t)base * 2;

    const int r_stage = lane >> 2;       // 0..15: which record's nf row I stage
    const int q_stage = lane & 3;        // 0..3: which quarter of the row

    float acc0 = 0.f, acc1 = 0.f;

    for (int c0i = 0; c0i < count; c0i += CH) {
        const int cc = min(CH, count - c0i);

        // ---- stage sender nf rows: 4 lanes per record ----
        // snd read from GLOBAL recs (qb.z = dword 6 of record)
        if (r_stage < cc) {
            const unsigned snd =
                reinterpret_cast<const unsigned*>(rp)[((size_t)c0i + r_stage) * 8 + 6];
            const float4* src = reinterpret_cast<const float4*>(node_feats)
                                + (size_t)snd * 8 + q_stage * 2;
            const float4 v0 = src[0];
            const float4 v1 = src[1];
            float* dst = &nf_lds[wv][r_stage][q_stage * 8];
            *reinterpret_cast<float4*>(dst)     = v0;
            *reinterpret_cast<float4*>(dst + 4) = v1;
        }

        // ---- compute: records via scalar loads, nf via LDS b32 ----
#pragma unroll 4
        for (int i = 0; i < cc; ++i) {
            const uint4 qa = rp[(size_t)(c0i + i) * 2 + 0];  // uniform -> s_load
            const uint4 qb = rp[(size_t)(c0i + i) * 2 + 1];  // uniform -> s_load

            float wAv = dot2h(qa.x, wpA[0], 0.f);
            wAv = dot2h(qa.y, wpA[1], wAv);
            wAv = dot2h(qa.z, wpA[2], wAv);
            wAv = dot2h(qa.w, wpA[3], wAv);
            float wBv = dot2h(qa.x, wpB[0], 0.f);
            wBv = dot2h(qa.y, wpB[1], wBv);
            wBv = dot2h(qa.z, wpB[2], wBv);
            wBv = dot2h(qa.w, wpB[3], wBv);

            // edge factor via one-hot fdot2 (no cvt, no selects)
            float fA = dot2h(qb.x, mA0, 0.f);
            fA = dot2h(qb.y, mA1, fA);
            fA = dot2h(qb.w, mA2, fA);
            float fB = dot2h(qb.x, mB0, 0.f);
            fB = dot2h(qb.y, mB1, fB);
            fB = dot2h(qb.w, mB2, fB);

            const float n0 = nf_lds[wv][i][iA];   // conflict-free
            const float n1 = nf_lds[wv][i][iB];   // broadcast groups

            acc0 = fmaf(wAv, n0 * fA, acc0);
            acc1 = fmaf(wBv, n1 * fB, acc1);
        }
    }

    // ---- epilogue: merge type2 triples, permute to output layout ----
    scr[wv][lane]      = acc0;
    scr[wv][64 + lane] = acc1;
    // same-wave LDS: no barrier needed, compiler inserts lgkmcnt waits
    float o0;
    if (lane < 16) {
        o0 = scr[wv][lane];
    } else if (lane < 24) {
        const int t = 16 + 3 * (lane - 16);
        o0 = scr[wv][t] + scr[wv][t + 1] + scr[wv][t + 2];
    } else {
        o0 = scr[wv][lane + 16];   // comps 24..47 <- slot0[40+..]; 48..63 <- slot1[0..15]
    }
    float* orow = out + (size_t)node * 96;
    orow[lane] = o0;
    if (lane < 32) orow[64 + lane] = scr[wv][80 + lane];  // comps 64..95 <- slot1[16..47]
}

extern "C" void kernel_launch(void* const* d_in, const int* in_sizes, int n_in,
                              void* d_out, int out_size, void* d_ws, size_t ws_size,
                              hipStream_t stream) {
    const float* node_feats    = (const float*)d_in[0];
    const float* edge_features = (const float*)d_in[1];
    const float* radial        = (const float*)d_in[2];
    const float* w1            = (const float*)d_in[3];
    const float* w2            = (const float*)d_in[4];
    const int*   senders       = (const int*)d_in[5];
    const int*   receivers     = (const int*)d_in[6];
    float* out = (float*)d_out;

    const int E = in_sizes[5];
    const int N = out_size / 96;
    const int eblocks = (E + 255) / 256;
    const int nblocks = (N + 3) / 4;   // 4 nodes/block, 1 wave/node

    const size_t recsBytes = (size_t)N * CAPACITY * 32;
    const size_t needPad   = recsBytes + (size_t)N * 16 * sizeof(int);
    const size_t needP1    = recsBytes + (size_t)N * sizeof(int);

    if (ws_size >= needPad) {
        // P1 + padded counters (1 per 64B line)
        uint4* recs = (uint4*)d_ws;
        int* cnt = (int*)((char*)d_ws + recsBytes);

        (void)hipMemsetAsync(cnt, 0, (size_t)N * 16 * sizeof(int), stream);
        hipLaunchKernelGGL(build_recs_kernel, dim3(eblocks), dim3(256), 0, stream,
                           edge_features, radial, w1, senders, receivers,
                           cnt, recs, E, CAPACITY, 16);
        hipLaunchKernelGGL((node_v15_kernel<true, 16>), dim3(nblocks), dim3(256), 0, stream,
                           node_feats, w2, cnt, recs, out, N);
    } else if (ws_size >= needP1) {
        // P1 unpadded
        uint4* recs = (uint4*)d_ws;
        int* cnt = (int*)((char*)d_ws + recsBytes);

        (void)hipMemsetAsync(cnt, 0, (size_t)N * sizeof(int), stream);
        hipLaunchKernelGGL(build_recs_kernel, dim3(eblocks), dim3(256), 0, stream,
                           edge_features, radial, w1, senders, receivers,
                           cnt, recs, E, CAPACITY, 1);
        hipLaunchKernelGGL((node_v15_kernel<true, 1>), dim3(nblocks), dim3(256), 0, stream,
                           node_feats, w2, cnt, recs, out, N);
    } else {
        // P2 fallback: counting sort. layout: recs[E*32] | cnt[N] | off[N+1] | cursor[N]
        uint4* recs = (uint4*)d_ws;
        int* cnt    = (int*)((char*)d_ws + (size_t)E * 32);
        int* off    = cnt + N;
        int* cursor = cnt + 2 * N + 1;

        (void)hipMemsetAsync(cnt, 0, (size_t)N * sizeof(int), stream);
        hipLaunchKernelGGL(hist_kernel, dim3(eblocks), dim3(256), 0, stream,
                           receivers, cnt, E);
        hipLaunchKernelGGL(scan_kernel, dim3(1), dim3(1024), 0, stream,
                           cnt, off, cursor, N);
        hipLaunchKernelGGL(build_recs_kernel, dim3(eblocks), dim3(256), 0, stream,
                           edge_features, radial, w1, senders, receivers,
                           cursor, recs, E, 0, 1);
        hipLaunchKernelGGL((node_v15_kernel<false, 1>), dim3(nblocks), dim3(256), 0, stream,
                           node_feats, w2, off, recs, out, N);
    }
}